// Round 4
// baseline (122.241 us; speedup 1.0000x reference)
//
#include <hip/hip_runtime.h>

// ---------------------------------------------------------------------------
// TaskAlignedAssigner (YOLO TAL) for MI355X.
// B=32, A=8400, M=32, C=80 (derived at runtime; M<=32 so a gt-column mask
// fits one uint32 per anchor; C%4==0 assumed for float4 ts writes).
//
// Outputs (concatenated float32, return order):
//   tl  (B,A)    off 0
//   tb  (B,A,4)  off BA
//   ts  (B,A,C)  off BA*5
//   fg  (B,A)    off BA*(5+C)
//   tgt (B,A)    off BA*(6+C)
//
// R1: removed global atomic histogram (65us same-cacheline serialization).
// R2: k_fix2 wave-parallel register scan (was 71.7us of dependent global
//     latency at 1% occupancy).
// R3: 7 launches -> 4. k_init folded into per-block inline mode detection
//     (mask_gt[.,0] is always true -> 1KB scan classifies dtype). k_select1
//     + fix1 folded into k_fix2 (select1's rowbits dedup-write is redundant:
//     final select's pc>1 full-row argmax is invariant to extra bits; tgt +
//     histogram live in LDS). hasin computed by k_inmask as a per-batch OR
//     ballot. k_ts fused into k_final via LDS staging. colreduce early-exits
//     masked-out gt columns (~48% of blocks).
// ---------------------------------------------------------------------------

#define EPS_IN   1e-9f
#define IOU_EPS  1e-7f

// IoU exactly as reference (_iou_xyxy) with clip(.,0); fp contraction off so
// results are bit-identical across kernels and match plain IEEE numpy eval.
__device__ __forceinline__ float iou_pair(const float4 p, const float4 g) {
#pragma clang fp contract(off)
    float w1 = p.z - p.x;
    float h1 = (p.w - p.y) + IOU_EPS;
    float w2 = g.z - g.x;
    float h2 = (g.w - g.y) + IOU_EPS;
    float iw = fminf(p.z, g.z) - fmaxf(p.x, g.x);
    iw = fmaxf(iw, 0.0f);
    float ih = fminf(p.w, g.w) - fmaxf(p.y, g.y);
    ih = fmaxf(ih, 0.0f);
    float inter = iw * ih;
    float uni = w1 * h1 + w2 * h2 - inter + IOU_EPS;
    float r = inter / uni;
    return fmaxf(r, 0.0f);
}

// mask_gt dtype detection, inline per block (replaces R2's k_init kernel).
// Scans the first nw words (nw = min(B*M/4,256) -> <= min buffer size in
// bytes for all candidate dtypes). int32 mask words are {0,1} -> mode 0;
// f32 words are {0, 0x3F800000} -> mode 1; byte-packed bool produces
// composite words (>1 and != 1.0f pattern) -> mode 2. mask[b][0] is always
// true (n_gt>=1) so each dtype is observable. Uniform across the block.
__device__ __forceinline__ int detect_mode(const void* mg, int nw) {
    const unsigned* w = (const unsigned*)mg;
    int lane = threadIdx.x & 63;
    int badI = 0, badF = 0;
    for (int i = lane; i < nw; i += 64) {
        unsigned v = w[i];
        badI |= (v > 1u);
        badF |= (v != 0u && v != 0x3F800000u);
    }
    unsigned long long bI = __ballot(badI != 0);
    unsigned long long bF = __ballot(badF != 0);
    return bI ? (bF ? 2 : 1) : 0;
}

__device__ __forceinline__ bool mask_at(const void* mg, int mode, int idx) {
    if (mode == 0) return ((const int*)mg)[idx] != 0;
    if (mode == 1) return ((const float*)mg)[idx] != 0.0f;
    return ((const unsigned char*)mg)[idx] != 0;
}

// K1: rowbits[b][a] = bitmask over m of (anchor inside gt m && mask_gt[m]);
// also hasinBits[b] |= OR of all rows (column-presence for fix1's need1).
__global__ void k_inmask(const float2* __restrict__ anc, const float4* __restrict__ gtb,
                         const void* mg, int nw,
                         unsigned* __restrict__ rowbits, unsigned* __restrict__ hasinBits,
                         int A, int M) {
    int b = blockIdx.y;
    int mode = detect_mode(mg, nw);
    int a = blockIdx.x * blockDim.x + threadIdx.x;
    __shared__ float4 sg[32];
    __shared__ unsigned char smg[32];
    __shared__ unsigned sOr[4];
    if (threadIdx.x < M) {
        sg[threadIdx.x]  = gtb[b * M + threadIdx.x];
        smg[threadIdx.x] = mask_at(mg, mode, b * M + threadIdx.x) ? 1 : 0;
    }
    __syncthreads();
    unsigned bits = 0u;
    if (a < A) {
        float2 an = anc[a];
        for (int m = 0; m < M; m++) {
            float4 g = sg[m];
            float mn = fminf(fminf(an.x - g.x, an.y - g.y), fminf(g.z - an.x, g.w - an.y));
            if (mn > EPS_IN && smg[m]) bits |= (1u << m);
        }
        rowbits[(size_t)b * A + a] = bits;
    }
    unsigned v = bits;
    for (int off = 32; off; off >>= 1) v |= __shfl_down(v, off);
    int lane = threadIdx.x & 63, wid = threadIdx.x >> 6;
    if (lane == 0) sOr[wid] = v;
    __syncthreads();
    if (threadIdx.x == 0) {
        unsigned o = sOr[0] | sOr[1] | sOr[2] | sOr[3];
        if (o) atomicOr(&hasinBits[b], o);
    }
}

// K2: per masked (b,m) column: argmax_a overlaps -> colKey (first-index
// tiebreak key). Unmasked columns exit immediately (colKey never read for
// them; stays at the 0xAA poison deterministically).
__global__ void k_colreduce(const float4* __restrict__ pdb, const float4* __restrict__ gtb,
                            const void* mg, int nw,
                            unsigned long long* __restrict__ colKey, int A, int M) {
    int b = blockIdx.y, m = blockIdx.x;
    int mode = detect_mode(mg, nw);
    if (!mask_at(mg, mode, b * M + m)) return;
    float4 g = gtb[b * M + m];
    unsigned long long key = 0ull;
    for (int a = threadIdx.x; a < A; a += blockDim.x) {
        float v = iou_pair(pdb[(size_t)b * A + a], g);
        unsigned long long k =
            ((unsigned long long)__float_as_uint(v) << 32) | (0xFFFFFFFFu - (unsigned)a);
        if (k > key) key = k;
    }
    __shared__ unsigned long long skey[4];
    int lane = threadIdx.x & 63, wid = threadIdx.x >> 6;
    for (int off = 32; off; off >>= 1) {
        unsigned long long o = __shfl_down(key, off);
        if (o > key) key = o;
    }
    if (lane == 0) skey[wid] = key;
    __syncthreads();
    if (threadIdx.x == 0) {
        int nwav = (int)(blockDim.x >> 6);
        for (int i = 1; i < nwav; i++) if (skey[i] > key) key = skey[i];
        colKey[b * M + m] = key;
    }
}

// K3: fused fix1 + select1 + fix2. One block per batch.
//  phase 0 (wave 0): prefetch colKey/mask/hasin; build need1 (fix1) compact
//    list of (anchor, gt) pairs.
//  phase 1 (all): anchor pass — bits = rowbits | fix1-bits; per-anchor tgt
//    (select1, LDS only) + LDS histogram; fix1 bits OR'd to global rowbits.
//  phase 2 (wave 0): wave-parallel order-dependent 32-step scan in registers
//    (lane m holds cl[m]); steal side effects are fire-and-forget atomicOr.
__global__ __launch_bounds__(1024) void k_fix2(
        const void* mg, int nw,
        const unsigned long long* __restrict__ colKey,
        const unsigned* __restrict__ hasinBits,
        const float4* __restrict__ pdb, const float4* __restrict__ gtb,
        unsigned* __restrict__ rowbits, int A, int M) {
    extern __shared__ short stgt[];           // A entries, -1..M-1
    __shared__ float4 sg[32];
    __shared__ int cl[32];
    __shared__ int sbest[32];
    __shared__ int fixA[32];
    __shared__ unsigned char fixG[32];
    __shared__ unsigned smaskbits;
    __shared__ int sL;
    int b = blockIdx.x, tid = threadIdx.x;
    int mode = detect_mode(mg, nw);
    if (tid < 32) { cl[tid] = 0; sbest[tid] = -1; }
    if (tid < M) sg[tid] = gtb[b * M + tid];
    if (tid < 64) {
        bool mv = false; int best = -1;
        if (tid < M) {
            mv = mask_at(mg, mode, b * M + tid);
            if (mv) {
                unsigned long long key = colKey[b * M + tid];
                best = (int)(0xFFFFFFFFu - (unsigned)(key & 0xFFFFFFFFull));
            }
        }
        unsigned hb = hasinBits[b];
        unsigned mb = (unsigned)__ballot(mv);
        bool need = mv && !((hb >> tid) & 1u);   // fix1: masked && no in-box anchor
        unsigned nb = (unsigned)__ballot(need);
        if (tid < M && mv) sbest[tid] = best;
        if (tid == 0) { smaskbits = mb; sL = __popc(nb); }
        if (need) {
            int pos = __popc(nb & ((1u << tid) - 1u));
            fixA[pos] = best; fixG[pos] = (unsigned char)tid;
        }
    }
    __syncthreads();
    int L = sL;
    for (int a = tid; a < A; a += blockDim.x) {
        size_t idx = (size_t)b * A + a;
        unsigned bits = rowbits[idx];
        unsigned add = 0u;
        for (int j = 0; j < L; j++) if (fixA[j] == a) add |= (1u << fixG[j]);
        if (add) { atomicOr(&rowbits[idx], add); bits |= add; }
        int pc = __popc(bits);
        int t;
        if (pc > 1) {
            float4 p = pdb[idx];
            float bv = -1.0f; int bm = 0;
            for (int m = 0; m < M; m++) {
                float v = iou_pair(p, sg[m]);
                if (v > bv) { bv = v; bm = m; }
            }
            t = bm;
        } else if (pc == 1) t = __ffs(bits) - 1;
        else t = -1;
        stgt[a] = (short)t;
        if (t >= 0) atomicAdd(&cl[t], 1);
    }
    __syncthreads();
    if (tid >= 64) return;
    int lane = tid;
    unsigned maskbits = smaskbits;
    int myBest = (lane < 32) ? sbest[lane] : -1;
    int myCnt  = (lane < 32) ? cl[lane]    : 0;
    int myPre  = (myBest >= 0 && myBest < A) ? (int)stgt[myBest] : -1;
    unsigned myEq = 0u;
    for (int g2 = 0; g2 < 32; g2++) {
        int bb = __shfl(myBest, g2);
        if (bb == myBest) myEq |= (1u << g2);
    }
    unsigned applied = 0u;
    for (int g = 0; g < M; g++) {
        int cg = __shfl(myCnt, g);
        if (((maskbits >> g) & 1u) && cg == 0) {
            int a       = __shfl(myBest, g);
            unsigned em = __shfl(myEq, g);
            unsigned x  = applied & em;
            int old;
            if (x) old = 31 - __clz(x);      // last earlier step that took this anchor
            else   old = __shfl(myPre, g);   // select1's owner (-1 = background)
            if (lane == old) myCnt--;
            if (lane == g)   myCnt++;
            applied |= (1u << g);
            if (lane == 0)
                atomicOr(&rowbits[(size_t)b * A + a], 1u << g);  // no return -> no stall
        }
    }
}

// K4: final select (#2) + all outputs. Per-anchor: derive tgt/fg/ov from
// rowbits (pc>1 -> full-row argmax, invariant to extra bits), single
// pd_scores gather, scalar outputs; then block-cooperative coalesced float4
// write of the ts one-hot rows from LDS-staged norm/tl.
__global__ void k_finalts(const float* __restrict__ pds, const float4* __restrict__ pdb,
                          const float4* __restrict__ gtb, const int* __restrict__ gtl,
                          const unsigned* __restrict__ rowbits, float* __restrict__ out,
                          int A, int M, int C, int B) {
    int b = blockIdx.y;
    int base = blockIdx.x * 256;
    int tid = threadIdx.x;
    int a = base + tid;
    __shared__ float4 sg[32];
    __shared__ int sl[32];
    __shared__ float snorm[256];
    __shared__ int stl[256];
    if (tid < M) { sg[tid] = gtb[b * M + tid]; sl[tid] = gtl[b * M + tid]; }
    __syncthreads();
    size_t BA = (size_t)B * A;
    if (a < A) {
        size_t idx = (size_t)b * A + a;
        unsigned bits = rowbits[idx];
        int pc = __popc(bits);
        int tgt, fg; float ov = 0.0f;
        float4 p = pdb[idx];
        if (pc > 1) {
            float bv = -1.0f; int bm = 0;
            for (int m = 0; m < M; m++) {
                float v = iou_pair(p, sg[m]);
                if (v > bv) { bv = v; bm = m; }
            }
            tgt = bm; fg = 1; ov = bv;
        } else if (pc == 1) {
            tgt = __ffs(bits) - 1; fg = 1;
            ov = iou_pair(p, sg[tgt]);
        } else { tgt = 0; fg = 0; }
        int lab = sl[tgt];
        int tl = min(max(lab, 0), C);            // clip(., 0, NUM_CLASSES)
        float norm = 0.0f;
        if (fg) {
            int li = (lab >= 0 && lab < C) ? lab : 0;
            float cls = pds[idx * (size_t)C + li];
            float ov6 = powf(ov, 6.0f);          // overlaps ** BETA
            float v = cls * ov6;                 // align_metric at (a, tgt)
            norm = v * ov / (v + 1e-9f);         // pam*pov/(pam+eps)
        }
        out[idx] = (float)tl;                                // tl
        ((float4*)(out + BA))[idx] = sg[tgt];                // tb
        out[BA * (size_t)(5 + C) + idx] = fg ? 1.0f : 0.0f;  // fg
        out[BA * (size_t)(6 + C) + idx] = (float)tgt;        // tgt
        snorm[tid] = norm;
        stl[tid] = tl;
    }
    __syncthreads();
    int cnt = min(256, A - base);
    int rowf4 = C >> 2;
    int nf4 = cnt * rowf4;
    float4* tsb = (float4*)(out + BA * 5 + ((size_t)b * A + base) * C);
    int row = tid / rowf4;
    int c4  = tid - row * rowf4;
    for (int i = tid; i < nf4; i += 256) {
        float nv = snorm[row];
        int tl   = stl[row];
        int cb = c4 * 4;
        float4 v;
        v.x = (tl == cb + 0) ? nv : 0.0f;
        v.y = (tl == cb + 1) ? nv : 0.0f;
        v.z = (tl == cb + 2) ? nv : 0.0f;
        v.w = (tl == cb + 3) ? nv : 0.0f;
        tsb[i] = v;
        // advance (i += 256) in (row, c4) space without division
        row += 12;                 // 256 = 12*rowf4 + 16 when rowf4 == 20
        c4  += 256 - 12 * rowf4;   // generic: works for any rowf4 via fixup below
        while (c4 >= rowf4) { c4 -= rowf4; row++; }
    }
}

extern "C" void kernel_launch(void* const* d_in, const int* in_sizes, int n_in,
                              void* d_out, int out_size, void* d_ws, size_t ws_size,
                              hipStream_t stream) {
    const float*  pd_scores = (const float*)d_in[0];
    const float4* pd_bboxes = (const float4*)d_in[1];
    const float2* anc       = (const float2*)d_in[2];
    const int*    gt_labels = (const int*)d_in[3];
    const float4* gt_bboxes = (const float4*)d_in[4];
    const void*   mask_gt   = d_in[5];

    int A = in_sizes[2] / 2;
    int B = in_sizes[1] / (A * 4);
    int M = in_sizes[3] / B;
    int C = (int)((long long)in_sizes[0] / ((long long)B * A));
    int nw = (B * M) / 4; if (nw > 256) nw = 256;

    char* wp = (char*)d_ws;
    auto carve = [&](size_t bytes) -> char* {
        char* r = wp; wp += (bytes + 255) & ~(size_t)255; return r;
    };
    unsigned* rowbits          = (unsigned*)carve((size_t)B * A * 4);
    unsigned long long* colKey = (unsigned long long*)carve((size_t)B * M * 8);
    unsigned* hasinBits        = (unsigned*)carve((size_t)B * 4);

    float* out = (float*)d_out;
    int nCh = (A + 255) / 256;
    dim3 gAB(nCh, B);
    dim3 gMB(M, B);

    hipMemsetAsync(hasinBits, 0, (size_t)B * 4, stream);
    k_inmask<<<gAB, 256, 0, stream>>>(anc, gt_bboxes, mask_gt, nw, rowbits, hasinBits, A, M);
    k_colreduce<<<gMB, 256, 0, stream>>>(pd_bboxes, gt_bboxes, mask_gt, nw, colKey, A, M);
    size_t sh = ((size_t)A * sizeof(short) + 7) & ~(size_t)7;
    k_fix2<<<B, 1024, sh, stream>>>(mask_gt, nw, colKey, hasinBits, pd_bboxes, gt_bboxes,
                                    rowbits, A, M);
    k_finalts<<<gAB, 256, 0, stream>>>(pd_scores, pd_bboxes, gt_bboxes, gt_labels,
                                       rowbits, out, A, M, C, B);
}

// Round 5
// 74.488 us; speedup vs baseline: 1.6411x; 1.6411x over previous
//
#include <hip/hip_runtime.h>

// ---------------------------------------------------------------------------
// TaskAlignedAssigner (YOLO TAL) for MI355X.
// B=32, A=8400, M=32, C=80 (derived at runtime; M<=32 so a gt-column mask
// fits one uint32 per anchor; C%4==0 assumed for float4 ts writes).
//
// Outputs (concatenated float32, return order):
//   tl  (B,A)    off 0
//   tb  (B,A,4)  off BA
//   ts  (B,A,C)  off BA*5
//   fg  (B,A)    off BA*(5+C)
//   tgt (B,A)    off BA*(6+C)
//
// R1: removed global atomic histogram (65us same-cacheline serialization).
// R2: k_fix2 wave-parallel register scan (was 71.7us dependent-latency).
// R3 (regressed, 122us): fused select1 into the 32-block k_fix2 -> the
//     pc>1 IoU argmax ran on 32/256 CUs (per-CU VALUBusy ~51%, 69us).
// R4: select1 back to full grid (per-anchor parallel work must stay on the
//     full chip); k_fix2 keeps only the truly-serial per-batch part
//     (histogram + register scan, ~32 atomicOrs, no tgtfg writes). Kept R3
//     wins: inline dtype detect, fix1 folded into colreduce via hasinBits,
//     colreduce early-exit, fused finalts.
// ---------------------------------------------------------------------------

#define EPS_IN   1e-9f
#define IOU_EPS  1e-7f

// IoU exactly as reference (_iou_xyxy) with clip(.,0); fp contraction off so
// results are bit-identical across kernels and match plain IEEE numpy eval.
__device__ __forceinline__ float iou_pair(const float4 p, const float4 g) {
#pragma clang fp contract(off)
    float w1 = p.z - p.x;
    float h1 = (p.w - p.y) + IOU_EPS;
    float w2 = g.z - g.x;
    float h2 = (g.w - g.y) + IOU_EPS;
    float iw = fminf(p.z, g.z) - fmaxf(p.x, g.x);
    iw = fmaxf(iw, 0.0f);
    float ih = fminf(p.w, g.w) - fmaxf(p.y, g.y);
    ih = fmaxf(ih, 0.0f);
    float inter = iw * ih;
    float uni = w1 * h1 + w2 * h2 - inter + IOU_EPS;
    float r = inter / uni;
    return fmaxf(r, 0.0f);
}

// mask_gt dtype detection, inline per block. Scans the first nw words.
// int32 mask words are {0,1} -> mode 0; f32 words are {0,0x3F800000} ->
// mode 1; byte-packed bool gives composite words -> mode 2. mask[b][0] is
// always true (n_gt>=1) so each dtype is observable. Wave-uniform result.
__device__ __forceinline__ int detect_mode(const void* mg, int nw) {
    const unsigned* w = (const unsigned*)mg;
    int lane = threadIdx.x & 63;
    int badI = 0, badF = 0;
    for (int i = lane; i < nw; i += 64) {
        unsigned v = w[i];
        badI |= (v > 1u);
        badF |= (v != 0u && v != 0x3F800000u);
    }
    unsigned long long bI = __ballot(badI != 0);
    unsigned long long bF = __ballot(badF != 0);
    return bI ? (bF ? 2 : 1) : 0;
}

__device__ __forceinline__ bool mask_at(const void* mg, int mode, int idx) {
    if (mode == 0) return ((const int*)mg)[idx] != 0;
    if (mode == 1) return ((const float*)mg)[idx] != 0.0f;
    return ((const unsigned char*)mg)[idx] != 0;
}

// K1: rowbits[b][a] = bitmask over m of (anchor inside gt m && mask_gt[m]);
// also hasinBits[b] |= OR of all rows (column-presence, for fix1's need1).
__global__ void k_inmask(const float2* __restrict__ anc, const float4* __restrict__ gtb,
                         const void* mg, int nw,
                         unsigned* __restrict__ rowbits, unsigned* __restrict__ hasinBits,
                         int A, int M) {
    int b = blockIdx.y;
    int mode = detect_mode(mg, nw);
    int a = blockIdx.x * blockDim.x + threadIdx.x;
    __shared__ float4 sg[32];
    __shared__ unsigned char smg[32];
    __shared__ unsigned sOr[4];
    if (threadIdx.x < M) {
        sg[threadIdx.x]  = gtb[b * M + threadIdx.x];
        smg[threadIdx.x] = mask_at(mg, mode, b * M + threadIdx.x) ? 1 : 0;
    }
    __syncthreads();
    unsigned bits = 0u;
    if (a < A) {
        float2 an = anc[a];
        for (int m = 0; m < M; m++) {
            float4 g = sg[m];
            float mn = fminf(fminf(an.x - g.x, an.y - g.y), fminf(g.z - an.x, g.w - an.y));
            if (mn > EPS_IN && smg[m]) bits |= (1u << m);
        }
        rowbits[(size_t)b * A + a] = bits;
    }
    unsigned v = bits;
    for (int off = 32; off; off >>= 1) v |= __shfl_down(v, off);
    int lane = threadIdx.x & 63, wid = threadIdx.x >> 6;
    if (lane == 0) sOr[wid] = v;
    __syncthreads();
    if (threadIdx.x == 0) {
        unsigned o = sOr[0] | sOr[1] | sOr[2] | sOr[3];
        if (o) atomicOr(&hasinBits[b], o);
    }
}

// K2: per masked (b,m) column: argmax_a overlaps -> colKey (first-index
// tiebreak key); fused fix1: if no anchor is inside this masked gt
// (hasinBits bit clear), OR bit m into the best anchor's row. Unmasked
// columns exit immediately (their colKey is never read).
__global__ void k_colreduce(const float4* __restrict__ pdb, const float4* __restrict__ gtb,
                            const void* mg, int nw,
                            const unsigned* __restrict__ hasinBits,
                            unsigned* __restrict__ rowbits,
                            unsigned long long* __restrict__ colKey, int A, int M) {
    int b = blockIdx.y, m = blockIdx.x;
    int mode = detect_mode(mg, nw);
    if (!mask_at(mg, mode, b * M + m)) return;
    float4 g = gtb[b * M + m];
    unsigned long long key = 0ull;
    for (int a = threadIdx.x; a < A; a += blockDim.x) {
        float v = iou_pair(pdb[(size_t)b * A + a], g);
        unsigned long long k =
            ((unsigned long long)__float_as_uint(v) << 32) | (0xFFFFFFFFu - (unsigned)a);
        if (k > key) key = k;
    }
    __shared__ unsigned long long skey[4];
    int lane = threadIdx.x & 63, wid = threadIdx.x >> 6;
    for (int off = 32; off; off >>= 1) {
        unsigned long long o = __shfl_down(key, off);
        if (o > key) key = o;
    }
    if (lane == 0) skey[wid] = key;
    __syncthreads();
    if (threadIdx.x == 0) {
        int nwav = (int)(blockDim.x >> 6);
        for (int i = 1; i < nwav; i++) if (skey[i] > key) key = skey[i];
        colKey[b * M + m] = key;
        if (!((hasinBits[b] >> m) & 1u)) {                       // fix1: need1
            unsigned besta = 0xFFFFFFFFu - (unsigned)(key & 0xFFFFFFFFull);
            atomicOr(&rowbits[(size_t)b * A + besta], 1u << m);  // no return -> no stall
        }
    }
}

// K3: select1 (full grid — the per-anchor IoU argmax must run on all CUs).
// tgtfg = per-anchor owner after dedup (-1 = background). rowbits is NOT
// deduped: the final select's pc>1 full-row argmax is invariant to extra
// bits (reference argmaxes the full overlaps row too).
__global__ void k_select1(const float4* __restrict__ pdb, const float4* __restrict__ gtb,
                          const unsigned* __restrict__ rowbits, int* __restrict__ tgtfg,
                          int A, int M) {
    int b = blockIdx.y;
    int a = blockIdx.x * blockDim.x + threadIdx.x;
    __shared__ float4 sg[32];
    if (threadIdx.x < M) sg[threadIdx.x] = gtb[b * M + threadIdx.x];
    __syncthreads();
    if (a >= A) return;
    size_t idx = (size_t)b * A + a;
    unsigned bits = rowbits[idx];
    int pc = __popc(bits);
    int t;
    if (pc > 1) {
        float4 p = pdb[idx];
        float bv = -1.0f; int bm = 0;
        for (int m = 0; m < M; m++) {
            float v = iou_pair(p, sg[m]);
            if (v > bv) { bv = v; bm = m; }
        }
        t = bm;
    } else if (pc == 1) {
        t = __ffs(bits) - 1;
    } else t = -1;
    tgtfg[idx] = t;
}

// K4: fix-2 — only the truly-serial per-batch work. One block per batch:
// phase 1 LDS-atomic histogram of tgtfg; phase 2 prefetch (32 scattered
// loads in parallel); phase 3 wave-parallel order-dependent 32-step scan in
// registers (lane m holds cl[m]; shfl-only deps). Global side effects are
// <=32 fire-and-forget atomicOrs into rowbits.
__global__ __launch_bounds__(1024) void k_fix2(
        const void* mg, int nw,
        const unsigned long long* __restrict__ colKey,
        const int* __restrict__ tgtfg,
        unsigned* __restrict__ rowbits, int A, int M) {
    int b = blockIdx.x, tid = threadIdx.x;
    __shared__ int cl[32];
    __shared__ int sbest[32];
    __shared__ int spre[32];
    __shared__ unsigned smaskbits;
    if (tid < 32) cl[tid] = 0;
    __syncthreads();
    // Phase 1: histogram (coalesced reads, LDS atomics only).
    for (int a = tid; a < A; a += blockDim.x) {
        int t = tgtfg[(size_t)b * A + a];
        if (t >= 0) atomicAdd(&cl[t], 1);
    }
    // Phase 2: prefetch scan inputs (first wave).
    if (tid < 64) {
        int mode = detect_mode(mg, nw);
        bool mv = false; int best = -1;
        if (tid < M) mv = mask_at(mg, mode, b * M + tid);
        if (mv) {
            unsigned long long key = colKey[b * M + tid];
            best = (int)(0xFFFFFFFFu - (unsigned)(key & 0xFFFFFFFFull));
        }
        if (tid < 32) { sbest[tid] = best; spre[tid] = (best >= 0) ? tgtfg[(size_t)b * A + best] : -1; }
        unsigned long long bal = __ballot(mv);
        if (tid == 0) smaskbits = (unsigned)bal;
    }
    __syncthreads();
    if (tid >= 64) return;
    // Phase 3: wave-parallel serial scan. Lane m (m<32) holds count of gt m.
    int lane = tid;
    unsigned maskbits = smaskbits;
    int myBest = (lane < 32) ? sbest[lane] : -1;
    int myCnt  = (lane < 32) ? cl[lane]    : 0;
    int myPre  = (lane < 32) ? spre[lane]  : -1;
    unsigned myEq = 0u;
    for (int g2 = 0; g2 < 32; g2++) {
        int bb = __shfl(myBest, g2);
        if (bb == myBest) myEq |= (1u << g2);
    }
    unsigned applied = 0u;
    for (int g = 0; g < M; g++) {
        int cg = __shfl(myCnt, g);
        if (((maskbits >> g) & 1u) && cg == 0) {
            int a       = __shfl(myBest, g);
            unsigned em = __shfl(myEq, g);
            unsigned x  = applied & em;
            int old;
            if (x) old = 31 - __clz(x);      // last earlier step that took this anchor
            else   old = __shfl(myPre, g);   // select1's owner (-1 = background)
            if (lane == old) myCnt--;
            if (lane == g)   myCnt++;
            applied |= (1u << g);
            if (lane == 0)
                atomicOr(&rowbits[(size_t)b * A + a], 1u << g);  // no return -> no stall
        }
    }
}

// K5: final select (#2) + all outputs. Per-anchor tgt/fg/ov from rowbits
// (pc>1 -> full-row argmax), single pd_scores gather, scalar outputs; then
// block-cooperative coalesced float4 write of ts from LDS-staged norm/tl.
__global__ void k_finalts(const float* __restrict__ pds, const float4* __restrict__ pdb,
                          const float4* __restrict__ gtb, const int* __restrict__ gtl,
                          const unsigned* __restrict__ rowbits, float* __restrict__ out,
                          int A, int M, int C, int B) {
    int b = blockIdx.y;
    int base = blockIdx.x * 256;
    int tid = threadIdx.x;
    int a = base + tid;
    __shared__ float4 sg[32];
    __shared__ int sl[32];
    __shared__ float snorm[256];
    __shared__ int stl[256];
    if (tid < M) { sg[tid] = gtb[b * M + tid]; sl[tid] = gtl[b * M + tid]; }
    __syncthreads();
    size_t BA = (size_t)B * A;
    if (a < A) {
        size_t idx = (size_t)b * A + a;
        unsigned bits = rowbits[idx];
        int pc = __popc(bits);
        int tgt, fg; float ov = 0.0f;
        float4 p = pdb[idx];
        if (pc > 1) {
            float bv = -1.0f; int bm = 0;
            for (int m = 0; m < M; m++) {
                float v = iou_pair(p, sg[m]);
                if (v > bv) { bv = v; bm = m; }
            }
            tgt = bm; fg = 1; ov = bv;
        } else if (pc == 1) {
            tgt = __ffs(bits) - 1; fg = 1;
            ov = iou_pair(p, sg[tgt]);
        } else { tgt = 0; fg = 0; }
        int lab = sl[tgt];
        int tl = min(max(lab, 0), C);            // clip(., 0, NUM_CLASSES)
        float norm = 0.0f;
        if (fg) {
            int li = (lab >= 0 && lab < C) ? lab : 0;
            float cls = pds[idx * (size_t)C + li];
            float ov6 = powf(ov, 6.0f);          // overlaps ** BETA
            float v = cls * ov6;                 // align_metric at (a, tgt)
            norm = v * ov / (v + 1e-9f);         // pam*pov/(pam+eps)
        }
        out[idx] = (float)tl;                                // tl
        ((float4*)(out + BA))[idx] = sg[tgt];                // tb
        out[BA * (size_t)(5 + C) + idx] = fg ? 1.0f : 0.0f;  // fg
        out[BA * (size_t)(6 + C) + idx] = (float)tgt;        // tgt
        snorm[tid] = norm;
        stl[tid] = tl;
    }
    __syncthreads();
    int cnt = min(256, A - base);
    int rowf4 = C >> 2;
    int nf4 = cnt * rowf4;
    float4* tsb = (float4*)(out + BA * 5 + ((size_t)b * A + base) * C);
    int q = 256 / rowf4, r = 256 - q * rowf4;
    int row = tid / rowf4;
    int c4  = tid - row * rowf4;
    for (int i = tid; i < nf4; i += 256) {
        float nv = snorm[row];
        int tl   = stl[row];
        int cb = c4 * 4;
        float4 v;
        v.x = (tl == cb + 0) ? nv : 0.0f;
        v.y = (tl == cb + 1) ? nv : 0.0f;
        v.z = (tl == cb + 2) ? nv : 0.0f;
        v.w = (tl == cb + 3) ? nv : 0.0f;
        tsb[i] = v;
        row += q; c4 += r;
        if (c4 >= rowf4) { c4 -= rowf4; row++; }
    }
}

extern "C" void kernel_launch(void* const* d_in, const int* in_sizes, int n_in,
                              void* d_out, int out_size, void* d_ws, size_t ws_size,
                              hipStream_t stream) {
    const float*  pd_scores = (const float*)d_in[0];
    const float4* pd_bboxes = (const float4*)d_in[1];
    const float2* anc       = (const float2*)d_in[2];
    const int*    gt_labels = (const int*)d_in[3];
    const float4* gt_bboxes = (const float4*)d_in[4];
    const void*   mask_gt   = d_in[5];

    int A = in_sizes[2] / 2;
    int B = in_sizes[1] / (A * 4);
    int M = in_sizes[3] / B;
    int C = (int)((long long)in_sizes[0] / ((long long)B * A));
    int nw = (B * M) / 4; if (nw > 256) nw = 256;

    char* wp = (char*)d_ws;
    auto carve = [&](size_t bytes) -> char* {
        char* r = wp; wp += (bytes + 255) & ~(size_t)255; return r;
    };
    unsigned* rowbits          = (unsigned*)carve((size_t)B * A * 4);
    int* tgtfg                 = (int*)carve((size_t)B * A * 4);
    unsigned long long* colKey = (unsigned long long*)carve((size_t)B * M * 8);
    unsigned* hasinBits        = (unsigned*)carve((size_t)B * 4);

    float* out = (float*)d_out;
    int nCh = (A + 255) / 256;
    dim3 gAB(nCh, B);
    dim3 gMB(M, B);

    hipMemsetAsync(hasinBits, 0, (size_t)B * 4, stream);
    k_inmask<<<gAB, 256, 0, stream>>>(anc, gt_bboxes, mask_gt, nw, rowbits, hasinBits, A, M);
    k_colreduce<<<gMB, 256, 0, stream>>>(pd_bboxes, gt_bboxes, mask_gt, nw, hasinBits,
                                         rowbits, colKey, A, M);
    k_select1<<<gAB, 256, 0, stream>>>(pd_bboxes, gt_bboxes, rowbits, tgtfg, A, M);
    k_fix2<<<B, 1024, 0, stream>>>(mask_gt, nw, colKey, tgtfg, rowbits, A, M);
    k_finalts<<<gAB, 256, 0, stream>>>(pd_scores, pd_bboxes, gt_bboxes, gt_labels,
                                       rowbits, out, A, M, C, B);
}